// Round 12
// baseline (702.263 us; speedup 1.0000x reference)
//
#include <hip/hip_runtime.h>

#define N_NODES 100000
#define N_EDGES 1600000
#define N_GRAPHS 512
#define DH 128
#define CAP 64             // per-node edge capacity in scratch (max in-deg ~42)
#define NLAYERS 6
#define NBUCK 196          // buckets of 512 nodes
#define BCAP 8960          // per-bucket edge capacity (mean 8163, +8 sigma)
#define CHUNK_A 4096
#define BLOCKS_A ((N_EDGES + CHUNK_A - 1) / CHUNK_A)   // 391
#define NROWS (N_NODES + 8)          // slice rows incl. sentinel zero-row at N_NODES
#define SENT_OFF (N_NODES << 5)      // sentinel byte-offset (points at zero row)
#define NT_TILES (N_NODES / 16)      // 6250
#define NGROUPS (N_NODES / 8)        // 12500

typedef short bf16x8 __attribute__((ext_vector_type(8)));
typedef float f32x4 __attribute__((ext_vector_type(4)));

// ---- bf16 helpers (RNE) ----
__device__ inline unsigned int pk_bf16x2(float a, float b) {
    unsigned int ua = __float_as_uint(a), ub = __float_as_uint(b);
    ua += 0x7fffu + ((ua >> 16) & 1u);
    ub += 0x7fffu + ((ub >> 16) & 1u);
    return (ua >> 16) | (ub & 0xffff0000u);
}
__device__ inline unsigned short bf16_rne(float f) {
    unsigned int u = __float_as_uint(f);
    u += 0x7fffu + ((u >> 16) & 1u);
    return (unsigned short)(u >> 16);
}
__device__ inline float bf_lo(unsigned int u) { return __uint_as_float(u << 16); }
__device__ inline float bf_hi(unsigned int u) { return __uint_as_float(u & 0xffff0000u); }

// ---- Pass A: radix partition edges into NBUCK buckets (by dst>>9), packed ----
// entry = (src << 9) | (dst & 511)
__global__ __launch_bounds__(256) void binA_kernel(const int* __restrict__ src,
                                                   const int* __restrict__ dst,
                                                   int* __restrict__ bcur,
                                                   int* __restrict__ part) {
    __shared__ int hist[NBUCK];
    __shared__ int base[NBUCK];
    int tid = threadIdx.x;
    int e0 = blockIdx.x * CHUNK_A;
    int myE = N_EDGES - e0; if (myE > CHUNK_A) myE = CHUNK_A;
    for (int b = tid; b < NBUCK; b += 256) hist[b] = 0;
    __syncthreads();
    for (int i = tid; i < myE; i += 256) {
        int d = dst[e0 + i];
        atomicAdd(&hist[d >> 9], 1);
    }
    __syncthreads();
    for (int b = tid; b < NBUCK; b += 256) {
        base[b] = atomicAdd(&bcur[b], hist[b]);
        hist[b] = 0;                      // reuse as local cursor
    }
    __syncthreads();
    for (int i = tid; i < myE; i += 256) {
        int s = src[e0 + i], d = dst[e0 + i];
        int b = d >> 9;
        int off = atomicAdd(&hist[b], 1);
        int pos = base[b] + off;
        if (pos < BCAP) part[(size_t)b * BCAP + pos] = (s << 9) | (d & 511);
    }
}

// ---- Pass B: scatter into CAP-padded scratch, then repack into DENSE
// interleaved layout: group g at dbase[g], entry order [eb][ln][ei]
// (8 iters x 8 nodes x 8 edges = 256B-contiguous per wave iteration).
__global__ __launch_bounds__(256) void binB_kernel(const int* __restrict__ part,
                                                   const int* __restrict__ bcur,
                                                   int* __restrict__ cnt,
                                                   int* __restrict__ scratch,
                                                   int* __restrict__ ginfo,
                                                   int* __restrict__ gcursor,
                                                   int* __restrict__ dense) {
    __shared__ int lcnt[512];
    __shared__ int goff[64];
    __shared__ int gmrs[64];
    __shared__ int bucket_base;
    int tid = threadIdx.x;
    int b = blockIdx.x;
    int node0 = b << 9;
    for (int i = tid; i < 512; i += 256) lcnt[i] = 0;
    __syncthreads();
    int m = bcur[b]; if (m > BCAP) m = BCAP;
    const int* p = part + (size_t)b * BCAP;
    for (int i = tid; i < m; i += 256) {
        int v = p[i];
        int dl = v & 511;
        int sv = (int)(((unsigned int)v) >> 9);
        int r = atomicAdd(&lcnt[dl], 1);
        if (r < CAP) scratch[(size_t)(node0 + dl) * CAP + r] = sv << 5;
    }
    __syncthreads();
    for (int i = tid; i < 512; i += 256) {
        int n = node0 + i;
        if (n < N_NODES) cnt[n] = lcnt[i];
    }
    if (tid < 64) {
        int gm = 0;
#pragma unroll
        for (int i = 0; i < 8; ++i) {
            int dg = lcnt[tid * 8 + i]; if (dg > CAP) dg = CAP;
            gm = max(gm, dg);
        }
        gmrs[tid] = (gm + 7) & ~7;
    }
    __syncthreads();
    if (tid == 0) {
        int acc = 0;
        for (int i = 0; i < 64; ++i) { goff[i] = acc; acc += gmrs[i] * 8; }
        bucket_base = atomicAdd(gcursor, acc);
    }
    __syncthreads();
    if (tid < 64) {
        int g0 = node0 + tid * 8;
        if (g0 < N_NODES) {
            int g = g0 >> 3;
            ginfo[g * 2] = bucket_base + goff[tid];
            ginfo[g * 2 + 1] = gmrs[tid];
        }
    }
    __syncthreads();
    // repack scratch -> dense (sentinels inserted here; no pre-padding needed)
    for (int gi = 0; gi < 64; ++gi) {
        int g0 = node0 + gi * 8;
        if (g0 >= N_NODES) break;
        int gmr = gmrs[gi];
        int total = gmr * 8;
        int* dst = dense + bucket_base + goff[gi];
        for (int w = tid; w < total; w += 256) {
            int eb = w >> 6, rem = w & 63, ln = rem >> 3, ei = rem & 7;
            int e = eb * 8 + ei;
            int dg = lcnt[gi * 8 + ln]; if (dg > CAP) dg = CAP;
            int v = (e < dg) ? scratch[(size_t)(g0 + ln) * CAP + e] : SENT_OFF;
            dst[w] = v;
        }
    }
}

// ---- dinv + zero the 8 sentinel rows (8 slices x 8 u32) ----
__global__ void dinv_kernel(const int* __restrict__ cnt, float* __restrict__ dinv,
                            unsigned int* __restrict__ hsb) {
    int n = blockIdx.x * 256 + threadIdx.x;
    if (n < N_NODES) dinv[n] = rsqrtf((float)(cnt[n] + 1));
    if (n < 64) hsb[((size_t)(n >> 3) * NROWS + N_NODES) * 8 + (n & 7)] = 0u;
}

// ---- W split: WThi/WTlo[l][c][k] = hi/lo bf16 of W_l[k][c] (transposed) ----
__global__ void wsplit_kernel(const float* __restrict__ w0, const float* __restrict__ ws,
                              unsigned short* __restrict__ wthi,
                              unsigned short* __restrict__ wtlo) {
    int i = blockIdx.x * 256 + threadIdx.x;
    if (i >= NLAYERS * DH * DH) return;
    int l = i >> 14;
    int r = i & 16383;
    int c = r >> 7, k = r & 127;
    const float* W = (l == 0) ? w0 : ws + (size_t)(l - 1) * DH * DH;
    float f = W[k * DH + c];
    unsigned short hi = bf16_rne(f);
    float hif = __uint_as_float(((unsigned int)hi) << 16);
    unsigned short lo = bf16_rne(f - hif);
    wthi[i] = hi;
    wtlo[i] = lo;
}

// ---- x fp32 -> packed bf16x2, SLICE-MAJOR: xb[(cu>>3)*N + node][cu&7] ----
__global__ void xconv_kernel(const float* __restrict__ x, unsigned int* __restrict__ xb) {
    int i = blockIdx.x * 256 + threadIdx.x;       // one uint2 (4 floats) per thread
    if (i >= N_NODES * 32) return;
    float4 v = *(const float4*)&x[(size_t)i * 4];
    int node = i >> 5;
    int cu = (i & 31) * 2;
    int ss = cu >> 3, o = cu & 7;
    uint2 ov = make_uint2(pk_bf16x2(v.x, v.y), pk_bf16x2(v.z, v.w));
    *(uint2*)&xb[((size_t)ss * N_NODES + node) * 8 + o] = ov;
}

// ---- MFMA GEMM, persistent with 2-DEEP tile prefetch: Yb (stride NROWS, sliced)
// block = 512 thr (8 waves); wave w owns output u32-cols [w*8, w*8+8) = slice w.
#define LOADB(v, kb, nd) \
    v = *(const bf16x8*)&Xb[(((size_t)(2*(kb) + (lk >> 1)) * N_NODES + (nd)) * 8) + (lk & 1) * 4];

__global__ __launch_bounds__(512) void mfma_gemm_kernel(const unsigned int* __restrict__ Xb,
                                                        const unsigned short* __restrict__ WThi,
                                                        const unsigned short* __restrict__ WTlo,
                                                        const float* __restrict__ dinv,
                                                        unsigned int* __restrict__ Yb) {
    int w = threadIdx.x >> 6;
    int lane = threadIdx.x & 63;
    int l15 = lane & 15, lk = lane >> 4;          // lk in 0..3
    int wc = w * 16 + l15;                        // A row (output dim)
    bf16x8 ahi[4], alo[4];
#pragma unroll
    for (int kb = 0; kb < 4; ++kb) {
        int k0 = kb * 32 + lk * 8;
        ahi[kb] = *(const bf16x8*)&WThi[wc * DH + k0];
        alo[kb] = *(const bf16x8*)&WTlo[wc * DH + k0];
    }
    int G = gridDim.x;
    int nt = blockIdx.x;
    if (nt >= NT_TILES) return;
    int node = nt * 16 + l15;
    bf16x8 b0, b1, b2, b3;
    LOADB(b0, 0, node); LOADB(b1, 1, node); LOADB(b2, 2, node); LOADB(b3, 3, node);
    float dnb = dinv[node];
    int nt1 = nt + G;
    bool h1 = nt1 < NT_TILES;
    int node1 = h1 ? nt1 * 16 + l15 : node;       // clamp: re-read hot lines
    bf16x8 c0, c1, c2, c3;
    LOADB(c0, 0, node1); LOADB(c1, 1, node1); LOADB(c2, 2, node1); LOADB(c3, 3, node1);
    float dnc = dinv[node1];
    for (;;) {
        int nt2 = nt1 + G;
        bool h2 = h1 && (nt2 < NT_TILES);
        int node2 = h2 ? nt2 * 16 + l15 : node1;  // clamp: hot
        bf16x8 e0, e1, e2, e3;
        LOADB(e0, 0, node2); LOADB(e1, 1, node2); LOADB(e2, 2, node2); LOADB(e3, 3, node2);
        float dne = dinv[node2];
        f32x4 acc = {0.f, 0.f, 0.f, 0.f};
        acc = __builtin_amdgcn_mfma_f32_16x16x32_bf16(ahi[0], b0, acc, 0, 0, 0);
        acc = __builtin_amdgcn_mfma_f32_16x16x32_bf16(alo[0], b0, acc, 0, 0, 0);
        acc = __builtin_amdgcn_mfma_f32_16x16x32_bf16(ahi[1], b1, acc, 0, 0, 0);
        acc = __builtin_amdgcn_mfma_f32_16x16x32_bf16(alo[1], b1, acc, 0, 0, 0);
        acc = __builtin_amdgcn_mfma_f32_16x16x32_bf16(ahi[2], b2, acc, 0, 0, 0);
        acc = __builtin_amdgcn_mfma_f32_16x16x32_bf16(alo[2], b2, acc, 0, 0, 0);
        acc = __builtin_amdgcn_mfma_f32_16x16x32_bf16(ahi[3], b3, acc, 0, 0, 0);
        acc = __builtin_amdgcn_mfma_f32_16x16x32_bf16(alo[3], b3, acc, 0, 0, 0);
        uint2 ov = make_uint2(pk_bf16x2(acc[0] * dnb, acc[1] * dnb),
                              pk_bf16x2(acc[2] * dnb, acc[3] * dnb));
        *(uint2*)&Yb[((size_t)w * NROWS + node) * 8 + lk * 2] = ov;   // slice w
        if (!h1) break;
        nt = nt1; node = node1; dnb = dnc;
        b0 = c0; b1 = c1; b2 = c2; b3 = c3;
        nt1 = nt2; node1 = node2; h1 = h2; dnc = dne;
        c0 = e0; c1 = e1; c2 = e2; c3 = e3;
    }
}

// ---- aggregation: dense stream + 2-deep in-loop index prefetch (clamped),
// hoisted epilogue loads. slice = blockIdx & 7; wave = 8 nodes x 8 u32-dims.
__global__ __launch_bounds__(256) void agg_kernel(const unsigned int* __restrict__ hs,
                                                  const int2* __restrict__ ginfo,
                                                  const int* __restrict__ dense,
                                                  const float* __restrict__ dinv,
                                                  const float* __restrict__ bias,
                                                  unsigned int* __restrict__ out) {
    int s = blockIdx.x & 7;
    int w = threadIdx.x >> 6;
    int lane = threadIdx.x & 63;
    int ln = lane >> 3, d = lane & 7;
    int node = (blockIdx.x >> 3) * 32 + w * 8 + ln;   // N_NODES = 32*3125: no tail
    int g = node >> 3;                                // wave-uniform
    int2 gi = ginfo[g];
    int dbase = __builtin_amdgcn_readfirstlane(gi.x);
    int gmr   = __builtin_amdgcn_readfirstlane(gi.y);
    const int4* r4 = (const int4*)(dense + dbase) + ln * 2;
    const char* hb = (const char*)(hs + (size_t)s * NROWS * 8);
    int d4 = d * 4;
    // hoisted epilogue operands (independent of gather loop)
    float dn = dinv[node];
    unsigned int us = *(const unsigned int*)(hb + ((node << 5) | d4));  // self term
    int col = s * 8 + d;
    float bx = bias[col * 2], by = bias[col * 2 + 1];
    float ax = 0.f, ay = 0.f;
    int iters = gmr >> 3;
    if (iters > 0) {
        int last = iters - 1;
        int k1 = (1 < last ? 1 : last) << 4;
        int4 a0 = r4[0], a1 = r4[1];
        int4 n0 = r4[k1], n1 = r4[k1 + 1];
        for (int k = 0; k < iters; ++k) {
            int kf = (k + 2 < last ? k + 2 : last) << 4;  // clamp: <=1-iter-old line
            int4 f0 = r4[kf], f1 = r4[kf + 1];
            unsigned int u0 = *(const unsigned int*)(hb + (a0.x | d4));
            unsigned int u1 = *(const unsigned int*)(hb + (a0.y | d4));
            unsigned int u2 = *(const unsigned int*)(hb + (a0.z | d4));
            unsigned int u3 = *(const unsigned int*)(hb + (a0.w | d4));
            unsigned int u4 = *(const unsigned int*)(hb + (a1.x | d4));
            unsigned int u5 = *(const unsigned int*)(hb + (a1.y | d4));
            unsigned int u6 = *(const unsigned int*)(hb + (a1.z | d4));
            unsigned int u7 = *(const unsigned int*)(hb + (a1.w | d4));
            ax += ((bf_lo(u0) + bf_lo(u1)) + (bf_lo(u2) + bf_lo(u3)))
                + ((bf_lo(u4) + bf_lo(u5)) + (bf_lo(u6) + bf_lo(u7)));
            ay += ((bf_hi(u0) + bf_hi(u1)) + (bf_hi(u2) + bf_hi(u3)))
                + ((bf_hi(u4) + bf_hi(u5)) + (bf_hi(u6) + bf_hi(u7)));
            a0 = n0; a1 = n1; n0 = f0; n1 = f1;
        }
    }
    float sx = ax + bf_lo(us), sy = ay + bf_hi(us);
    float ox = fmaxf(fmaf(sx, dn, bx), 0.f);
    float oy = fmaxf(fmaf(sy, dn, by), 0.f);
    out[((size_t)s * N_NODES + node) * 8 + d] = pk_bf16x2(ox, oy);
}

// ---- graph boundaries from sorted batch ----
__global__ void gptr_kernel(const int* __restrict__ batch, int* __restrict__ gptr) {
    int n = blockIdx.x * 256 + threadIdx.x;
    if (n >= N_NODES) return;
    int b1 = batch[n];
    if (n == 0) {
        for (int g = 0; g <= b1; ++g) gptr[g] = 0;
    } else {
        int b0 = batch[n - 1];
        for (int g = b0 + 1; g <= b1; ++g) gptr[g] = n;
    }
    if (n == N_NODES - 1) {
        for (int g = b1 + 1; g <= N_GRAPHS; ++g) gptr[g] = N_NODES;
    }
}

// ---- pooling + linear head (reads sliced packed bf16 h) ----
__global__ __launch_bounds__(256) void pool_kernel(const unsigned int* __restrict__ h,
                                                   const int* __restrict__ gptr,
                                                   const float* __restrict__ lin_w,
                                                   const float* __restrict__ lin_b,
                                                   float* __restrict__ out) {
    __shared__ float part[4];
    int g = blockIdx.x;
    int s = gptr[g], epos = gptr[g + 1];
    int w = threadIdx.x >> 6, lane = threadIdx.x & 63;
    size_t sbase = (size_t)(lane >> 3) * N_NODES * 8 + (lane & 7);
    float2 wv = *(const float2*)(lin_w + lane * 2);
    float acc = 0.f;
    for (int n = s + w; n < epos; n += 4) {
        unsigned int u = h[sbase + (size_t)n * 8];
        acc += bf_lo(u) * wv.x + bf_hi(u) * wv.y;
    }
#pragma unroll
    for (int off = 32; off > 0; off >>= 1) acc += __shfl_down(acc, off, 64);
    if (lane == 0) part[w] = acc;
    __syncthreads();
    if (threadIdx.x == 0) {
        float t = (part[0] + part[1]) + (part[2] + part[3]);
        float c = (float)(epos - s);
        if (c < 1.f) c = 1.f;
        out[g] = t / c + lin_b[0];
    }
}

extern "C" void kernel_launch(void* const* d_in, const int* in_sizes, int n_in,
                              void* d_out, int out_size, void* d_ws, size_t ws_size,
                              hipStream_t stream) {
    const float* x       = (const float*)d_in[0];
    const int*   eidx    = (const int*)d_in[1];
    const int*   batch   = (const int*)d_in[2];
    const float* conv_w0 = (const float*)d_in[3];
    const float* conv_b0 = (const float*)d_in[4];
    const float* conv_ws = (const float*)d_in[5];
    const float* conv_bs = (const float*)d_in[6];
    const float* lin_w   = (const float*)d_in[7];
    const float* lin_b   = (const float*)d_in[8];
    const int* srcI = eidx;
    const int* dstI = eidx + N_EDGES;

    char* ws = (char*)d_ws;
    size_t off = 0;
    auto alloc = [&](size_t bytes) {
        void* p = ws + off;
        off += (bytes + 255) & ~(size_t)255;
        return p;
    };
    unsigned int*  xb      = (unsigned int*)alloc((size_t)N_NODES * 64 * 4);   // sliced bf16x2 h
    unsigned int*  hsb     = (unsigned int*)alloc((size_t)8 * NROWS * 8 * 4);  // sliced + sentinel
    int*           scratch = (int*)alloc((size_t)N_NODES * CAP * 4);
    int*           dense   = (int*)alloc((size_t)N_NODES * CAP * 4);           // hard upper bound
    int*           part    = (int*)alloc((size_t)NBUCK * BCAP * 4);
    int*           cnt     = (int*)alloc((size_t)N_NODES * 4);
    float*         dinv    = (float*)alloc((size_t)N_NODES * 4);
    int*           bcur    = (int*)alloc((size_t)(NBUCK + 1) * 4);  // +1: dense cursor
    int*           gptr    = (int*)alloc((size_t)(N_GRAPHS + 1) * 4);
    int*           ginfo   = (int*)alloc((size_t)NGROUPS * 2 * 4);
    unsigned short* wthi = (unsigned short*)alloc((size_t)NLAYERS * DH * DH * 2);
    unsigned short* wtlo = (unsigned short*)alloc((size_t)NLAYERS * DH * DH * 2);
    int* gcursor = bcur + NBUCK;
    (void)ws_size; (void)in_sizes; (void)n_in; (void)out_size;

    hipMemsetAsync(bcur, 0, (size_t)(NBUCK + 1) * 4, stream);

    binA_kernel<<<BLOCKS_A, 256, 0, stream>>>(srcI, dstI, bcur, part);
    binB_kernel<<<NBUCK, 256, 0, stream>>>(part, bcur, cnt, scratch, ginfo, gcursor, dense);
    dinv_kernel<<<(N_NODES + 255) / 256, 256, 0, stream>>>(cnt, dinv, hsb);
    gptr_kernel<<<(N_NODES + 255) / 256, 256, 0, stream>>>(batch, gptr);
    wsplit_kernel<<<(NLAYERS * DH * DH + 255) / 256, 256, 0, stream>>>(conv_w0, conv_ws,
                                                                       wthi, wtlo);
    xconv_kernel<<<(N_NODES * 32 + 255) / 256, 256, 0, stream>>>(x, xb);

    for (int l = 0; l < NLAYERS; ++l) {
        const float* b = (l == 0) ? conv_b0 : conv_bs + (size_t)(l - 1) * DH;
        mfma_gemm_kernel<<<1280, 512, 0, stream>>>(xb, wthi + (size_t)l * DH * DH,
                                                   wtlo + (size_t)l * DH * DH, dinv, hsb);
        agg_kernel<<<8 * (NGROUPS / 4), 256, 0, stream>>>(hsb, (const int2*)ginfo, dense,
                                                          dinv, b, xb);
    }

    pool_kernel<<<N_GRAPHS, 256, 0, stream>>>(xb, gptr, lin_w, lin_b, (float*)d_out);
}

// Round 13
// 659.457 us; speedup vs baseline: 1.0649x; 1.0649x over previous
//
#include <hip/hip_runtime.h>

#define N_NODES 100000
#define N_EDGES 1600000
#define N_GRAPHS 512
#define DH 128
#define CAP 64             // per-node edge capacity in scratch (max in-deg ~42)
#define NLAYERS 6
#define NBUCK 196          // buckets of 512 nodes
#define BCAP 8960          // per-bucket edge capacity (mean 8163, +8 sigma)
#define CHUNK_A 4096
#define BLOCKS_A ((N_EDGES + CHUNK_A - 1) / CHUNK_A)   // 391
#define SENT_OFF (N_NODES << 8)      // sentinel byte-offset -> zero row at N_NODES
#define NT_TILES (N_NODES / 16)      // 6250

typedef short bf16x8 __attribute__((ext_vector_type(8)));
typedef float f32x4 __attribute__((ext_vector_type(4)));

// ---- bf16 helpers (RNE) ----
__device__ inline unsigned int pk_bf16x2(float a, float b) {
    unsigned int ua = __float_as_uint(a), ub = __float_as_uint(b);
    ua += 0x7fffu + ((ua >> 16) & 1u);
    ub += 0x7fffu + ((ub >> 16) & 1u);
    return (ua >> 16) | (ub & 0xffff0000u);
}
__device__ inline unsigned short bf16_rne(float f) {
    unsigned int u = __float_as_uint(f);
    u += 0x7fffu + ((u >> 16) & 1u);
    return (unsigned short)(u >> 16);
}
__device__ inline float bf_lo(unsigned int u) { return __uint_as_float(u << 16); }
__device__ inline float bf_hi(unsigned int u) { return __uint_as_float(u & 0xffff0000u); }

// ---- Pass A: radix partition edges into NBUCK buckets (by dst>>9), packed ----
// entry = (src << 9) | (dst & 511)
__global__ __launch_bounds__(256) void binA_kernel(const int* __restrict__ src,
                                                   const int* __restrict__ dst,
                                                   int* __restrict__ bcur,
                                                   int* __restrict__ part) {
    __shared__ int hist[NBUCK];
    __shared__ int base[NBUCK];
    int tid = threadIdx.x;
    int e0 = blockIdx.x * CHUNK_A;
    int myE = N_EDGES - e0; if (myE > CHUNK_A) myE = CHUNK_A;
    for (int b = tid; b < NBUCK; b += 256) hist[b] = 0;
    __syncthreads();
    for (int i = tid; i < myE; i += 256) {
        int d = dst[e0 + i];
        atomicAdd(&hist[d >> 9], 1);
    }
    __syncthreads();
    for (int b = tid; b < NBUCK; b += 256) {
        base[b] = atomicAdd(&bcur[b], hist[b]);
        hist[b] = 0;                      // reuse as local cursor
    }
    __syncthreads();
    for (int i = tid; i < myE; i += 256) {
        int s = src[e0 + i], d = dst[e0 + i];
        int b = d >> 9;
        int off = atomicAdd(&hist[b], 1);
        int pos = base[b] + off;
        if (pos < BCAP) part[(size_t)b * BCAP + pos] = (s << 9) | (d & 511);
    }
}

// ---- Pass B: scatter into CAP-padded scratch (entries = src<<8 byte offsets),
// then repack into DENSE per-node stream padded to round8(deg) with sentinels.
// ninfo[n] = {dense base, round8(deg)}.
__global__ __launch_bounds__(256) void binB_kernel(const int* __restrict__ part,
                                                   const int* __restrict__ bcur,
                                                   int* __restrict__ cnt,
                                                   int* __restrict__ scratch,
                                                   int2* __restrict__ ninfo,
                                                   int* __restrict__ gcursor,
                                                   int* __restrict__ dense) {
    __shared__ int lcnt[512];
    __shared__ int nbase[512];
    __shared__ int psum[64];
    __shared__ int bucket_base;
    int tid = threadIdx.x;
    int b = blockIdx.x;
    int node0 = b << 9;
    for (int i = tid; i < 512; i += 256) lcnt[i] = 0;
    __syncthreads();
    int m = bcur[b]; if (m > BCAP) m = BCAP;
    const int* p = part + (size_t)b * BCAP;
    for (int i = tid; i < m; i += 256) {
        int v = p[i];
        int dl = v & 511;
        int sv = (int)(((unsigned int)v) >> 9);
        int r = atomicAdd(&lcnt[dl], 1);
        if (r < CAP) scratch[(size_t)(node0 + dl) * CAP + r] = sv << 8;
    }
    __syncthreads();
    for (int i = tid; i < 512; i += 256) {
        int n = node0 + i;
        if (n < N_NODES) cnt[n] = lcnt[i];
    }
    if (tid < 64) {
        int acc = 0;
        int base = tid * 8;
#pragma unroll
        for (int i = 0; i < 8; ++i) {
            int dg = lcnt[base + i]; if (dg > CAP) dg = CAP;
            acc += (dg + 7) & ~7;
        }
        psum[tid] = acc;
    }
    __syncthreads();
    if (tid == 0) {
        int acc = 0;
        for (int i = 0; i < 64; ++i) { int t = psum[i]; psum[i] = acc; acc += t; }
        bucket_base = atomicAdd(gcursor, acc);
    }
    __syncthreads();
    if (tid < 64) {
        int off = psum[tid];
        int base = tid * 8;
#pragma unroll
        for (int i = 0; i < 8; ++i) {
            int dg = lcnt[base + i]; if (dg > CAP) dg = CAP;
            nbase[base + i] = off;
            off += (dg + 7) & ~7;
        }
    }
    __syncthreads();
    int bb = bucket_base;
    for (int i = tid; i < 512; i += 256) {
        int n = node0 + i;
        if (n < N_NODES) {
            int dg = lcnt[i]; if (dg > CAP) dg = CAP;
            ninfo[n] = make_int2(bb + nbase[i], (dg + 7) & ~7);
        }
    }
    // repack: 32 nodes per round, 8 threads per node
    for (int nb = 0; nb < 512; nb += 32) {
        int nl = nb + (tid >> 3);
        int n = node0 + nl;
        if (n < N_NODES) {
            int dg = lcnt[nl]; if (dg > CAP) dg = CAP;
            int r8 = (dg + 7) & ~7;
            int* dst = dense + bb + nbase[nl];
            for (int e = tid & 7; e < r8; e += 8)
                dst[e] = (e < dg) ? scratch[(size_t)n * CAP + e] : SENT_OFF;
        }
    }
}

// ---- dinv + zero the sentinel row (64 u32) ----
__global__ void dinv_kernel(const int* __restrict__ cnt, float* __restrict__ dinv,
                            unsigned int* __restrict__ hsb) {
    int n = blockIdx.x * 256 + threadIdx.x;
    if (n < N_NODES) dinv[n] = rsqrtf((float)(cnt[n] + 1));
    if (n < 64) hsb[(size_t)N_NODES * 64 + n] = 0u;
}

// ---- W split: WThi/WTlo[l][c][k] = hi/lo bf16 of W_l[k][c] (transposed) ----
__global__ void wsplit_kernel(const float* __restrict__ w0, const float* __restrict__ ws,
                              unsigned short* __restrict__ wthi,
                              unsigned short* __restrict__ wtlo) {
    int i = blockIdx.x * 256 + threadIdx.x;
    if (i >= NLAYERS * DH * DH) return;
    int l = i >> 14;
    int r = i & 16383;
    int c = r >> 7, k = r & 127;
    const float* W = (l == 0) ? w0 : ws + (size_t)(l - 1) * DH * DH;
    float f = W[k * DH + c];
    unsigned short hi = bf16_rne(f);
    float hif = __uint_as_float(((unsigned int)hi) << 16);
    unsigned short lo = bf16_rne(f - hif);
    wthi[i] = hi;
    wtlo[i] = lo;
}

// ---- x fp32 -> packed bf16x2, row-major [N][64] u32 ----
__global__ void xconv_kernel(const float* __restrict__ x, unsigned int* __restrict__ xb) {
    int i = blockIdx.x * 256 + threadIdx.x;       // one uint2 (4 floats) per thread
    if (i >= N_NODES * 32) return;
    float4 v = *(const float4*)&x[(size_t)i * 4];
    uint2 ov = make_uint2(pk_bf16x2(v.x, v.y), pk_bf16x2(v.z, v.w));
    *(uint2*)&xb[(size_t)i * 2] = ov;
}

// ---- MFMA GEMM with next-tile prefetch (round-8 structure), row-major I/O ----
// block = 512 thr (8 waves); wave w owns output u32-cols [w*8, w*8+8).
#define LOADB(v, kb, nd) \
    v = *(const bf16x8*)&Xb[(size_t)(nd) * 64 + (kb) * 16 + lk * 4];

__global__ __launch_bounds__(512) void mfma_gemm_kernel(const unsigned int* __restrict__ Xb,
                                                        const unsigned short* __restrict__ WThi,
                                                        const unsigned short* __restrict__ WTlo,
                                                        const float* __restrict__ dinv,
                                                        unsigned int* __restrict__ Yb) {
    int w = threadIdx.x >> 6;
    int lane = threadIdx.x & 63;
    int l15 = lane & 15, lk = lane >> 4;          // lk in 0..3
    int wc = w * 16 + l15;                        // A row (output dim)
    bf16x8 ahi[4], alo[4];
#pragma unroll
    for (int kb = 0; kb < 4; ++kb) {
        int k0 = kb * 32 + lk * 8;
        ahi[kb] = *(const bf16x8*)&WThi[wc * DH + k0];
        alo[kb] = *(const bf16x8*)&WTlo[wc * DH + k0];
    }
    int nt = blockIdx.x;
    if (nt >= NT_TILES) return;
    int node = nt * 16 + l15;
    bf16x8 b0, b1, b2, b3;
    LOADB(b0, 0, node); LOADB(b1, 1, node); LOADB(b2, 2, node); LOADB(b3, 3, node);
    for (;;) {
        int ntn = nt + gridDim.x;
        bool hn = ntn < NT_TILES;
        int noden = ntn * 16 + l15;
        bf16x8 n0 = b0, n1 = b1, n2 = b2, n3 = b3;
        if (hn) { LOADB(n0, 0, noden); LOADB(n1, 1, noden); LOADB(n2, 2, noden); LOADB(n3, 3, noden); }
        float dn = dinv[node];
        f32x4 acc = {0.f, 0.f, 0.f, 0.f};
        acc = __builtin_amdgcn_mfma_f32_16x16x32_bf16(ahi[0], b0, acc, 0, 0, 0);
        acc = __builtin_amdgcn_mfma_f32_16x16x32_bf16(alo[0], b0, acc, 0, 0, 0);
        acc = __builtin_amdgcn_mfma_f32_16x16x32_bf16(ahi[1], b1, acc, 0, 0, 0);
        acc = __builtin_amdgcn_mfma_f32_16x16x32_bf16(alo[1], b1, acc, 0, 0, 0);
        acc = __builtin_amdgcn_mfma_f32_16x16x32_bf16(ahi[2], b2, acc, 0, 0, 0);
        acc = __builtin_amdgcn_mfma_f32_16x16x32_bf16(alo[2], b2, acc, 0, 0, 0);
        acc = __builtin_amdgcn_mfma_f32_16x16x32_bf16(ahi[3], b3, acc, 0, 0, 0);
        acc = __builtin_amdgcn_mfma_f32_16x16x32_bf16(alo[3], b3, acc, 0, 0, 0);
        uint2 ov = make_uint2(pk_bf16x2(acc[0] * dn, acc[1] * dn),
                              pk_bf16x2(acc[2] * dn, acc[3] * dn));
        *(uint2*)&Yb[(size_t)node * 64 + w * 8 + lk * 2] = ov;
        if (!hn) break;
        nt = ntn; node = noden; b0 = n0; b1 = n1; b2 = n2; b3 = n3;
    }
}

// ---- aggregation: wave = 1 node, full-row gathers (256B/instr, 2 lines/edge),
// dense per-node sentinel-padded indices via SCALAR loads, hoisted epilogue ----
__global__ __launch_bounds__(256) void agg_kernel(const unsigned int* __restrict__ hs,
                                                  const int2* __restrict__ ninfo,
                                                  const int* __restrict__ dense,
                                                  const float* __restrict__ dinv,
                                                  const float* __restrict__ bias,
                                                  unsigned int* __restrict__ out) {
    int node = blockIdx.x * 4 + (threadIdx.x >> 6);
    if (node >= N_NODES) return;
    int lane = threadIdx.x & 63;
    int2 gi = ninfo[node];
    int dbase = __builtin_amdgcn_readfirstlane(gi.x);
    int r8d   = __builtin_amdgcn_readfirstlane(gi.y);
    const int* row = dense + dbase;                // wave-uniform -> scalar loads
    const char* hb = (const char*)hs;
    int l4 = lane * 4;
    // hoisted epilogue operands
    float dn = dinv[node];
    unsigned int us = hs[(size_t)node * 64 + lane];    // self term
    float bx = bias[lane * 2], by = bias[lane * 2 + 1];
    float ax = 0.f, ay = 0.f;
    for (int e = 0; e < r8d; e += 8) {
        int o0 = row[e + 0], o1 = row[e + 1], o2 = row[e + 2], o3 = row[e + 3];
        int o4 = row[e + 4], o5 = row[e + 5], o6 = row[e + 6], o7 = row[e + 7];
        unsigned int u0 = *(const unsigned int*)(hb + (o0 + l4));
        unsigned int u1 = *(const unsigned int*)(hb + (o1 + l4));
        unsigned int u2 = *(const unsigned int*)(hb + (o2 + l4));
        unsigned int u3 = *(const unsigned int*)(hb + (o3 + l4));
        unsigned int u4 = *(const unsigned int*)(hb + (o4 + l4));
        unsigned int u5 = *(const unsigned int*)(hb + (o5 + l4));
        unsigned int u6 = *(const unsigned int*)(hb + (o6 + l4));
        unsigned int u7 = *(const unsigned int*)(hb + (o7 + l4));
        ax += ((bf_lo(u0) + bf_lo(u1)) + (bf_lo(u2) + bf_lo(u3)))
            + ((bf_lo(u4) + bf_lo(u5)) + (bf_lo(u6) + bf_lo(u7)));
        ay += ((bf_hi(u0) + bf_hi(u1)) + (bf_hi(u2) + bf_hi(u3)))
            + ((bf_hi(u4) + bf_hi(u5)) + (bf_hi(u6) + bf_hi(u7)));
    }
    float sx = ax + bf_lo(us), sy = ay + bf_hi(us);
    float ox = fmaxf(fmaf(sx, dn, bx), 0.f);
    float oy = fmaxf(fmaf(sy, dn, by), 0.f);
    out[(size_t)node * 64 + lane] = pk_bf16x2(ox, oy);
}

// ---- graph boundaries from sorted batch ----
__global__ void gptr_kernel(const int* __restrict__ batch, int* __restrict__ gptr) {
    int n = blockIdx.x * 256 + threadIdx.x;
    if (n >= N_NODES) return;
    int b1 = batch[n];
    if (n == 0) {
        for (int g = 0; g <= b1; ++g) gptr[g] = 0;
    } else {
        int b0 = batch[n - 1];
        for (int g = b0 + 1; g <= b1; ++g) gptr[g] = n;
    }
    if (n == N_NODES - 1) {
        for (int g = b1 + 1; g <= N_GRAPHS; ++g) gptr[g] = N_NODES;
    }
}

// ---- pooling + linear head (reads row-major packed bf16 h) ----
__global__ __launch_bounds__(256) void pool_kernel(const unsigned int* __restrict__ h,
                                                   const int* __restrict__ gptr,
                                                   const float* __restrict__ lin_w,
                                                   const float* __restrict__ lin_b,
                                                   float* __restrict__ out) {
    __shared__ float part[4];
    int g = blockIdx.x;
    int s = gptr[g], epos = gptr[g + 1];
    int w = threadIdx.x >> 6, lane = threadIdx.x & 63;
    float2 wv = *(const float2*)(lin_w + lane * 2);
    float acc = 0.f;
    for (int n = s + w; n < epos; n += 4) {
        unsigned int u = h[(size_t)n * 64 + lane];
        acc += bf_lo(u) * wv.x + bf_hi(u) * wv.y;
    }
#pragma unroll
    for (int off = 32; off > 0; off >>= 1) acc += __shfl_down(acc, off, 64);
    if (lane == 0) part[w] = acc;
    __syncthreads();
    if (threadIdx.x == 0) {
        float t = (part[0] + part[1]) + (part[2] + part[3]);
        float c = (float)(epos - s);
        if (c < 1.f) c = 1.f;
        out[g] = t / c + lin_b[0];
    }
}

extern "C" void kernel_launch(void* const* d_in, const int* in_sizes, int n_in,
                              void* d_out, int out_size, void* d_ws, size_t ws_size,
                              hipStream_t stream) {
    const float* x       = (const float*)d_in[0];
    const int*   eidx    = (const int*)d_in[1];
    const int*   batch   = (const int*)d_in[2];
    const float* conv_w0 = (const float*)d_in[3];
    const float* conv_b0 = (const float*)d_in[4];
    const float* conv_ws = (const float*)d_in[5];
    const float* conv_bs = (const float*)d_in[6];
    const float* lin_w   = (const float*)d_in[7];
    const float* lin_b   = (const float*)d_in[8];
    const int* srcI = eidx;
    const int* dstI = eidx + N_EDGES;

    char* ws = (char*)d_ws;
    size_t off = 0;
    auto alloc = [&](size_t bytes) {
        void* p = ws + off;
        off += (bytes + 255) & ~(size_t)255;
        return p;
    };
    unsigned int*  xb      = (unsigned int*)alloc((size_t)(N_NODES + 1) * 64 * 4);
    unsigned int*  hsb     = (unsigned int*)alloc((size_t)(N_NODES + 1) * 64 * 4);
    int*           scratch = (int*)alloc((size_t)N_NODES * CAP * 4);
    int*           dense   = (int*)alloc((size_t)(N_EDGES + 8 * N_NODES) * 4);
    int*           part    = (int*)alloc((size_t)NBUCK * BCAP * 4);
    int*           cnt     = (int*)alloc((size_t)N_NODES * 4);
    float*         dinv    = (float*)alloc((size_t)N_NODES * 4);
    int*           bcur    = (int*)alloc((size_t)(NBUCK + 1) * 4);  // +1: dense cursor
    int*           gptr    = (int*)alloc((size_t)(N_GRAPHS + 1) * 4);
    int2*          ninfo   = (int2*)alloc((size_t)N_NODES * 8);
    unsigned short* wthi = (unsigned short*)alloc((size_t)NLAYERS * DH * DH * 2);
    unsigned short* wtlo = (unsigned short*)alloc((size_t)NLAYERS * DH * DH * 2);
    int* gcursor = bcur + NBUCK;
    (void)ws_size; (void)in_sizes; (void)n_in; (void)out_size;

    hipMemsetAsync(bcur, 0, (size_t)(NBUCK + 1) * 4, stream);

    binA_kernel<<<BLOCKS_A, 256, 0, stream>>>(srcI, dstI, bcur, part);
    binB_kernel<<<NBUCK, 256, 0, stream>>>(part, bcur, cnt, scratch, ninfo, gcursor, dense);
    dinv_kernel<<<(N_NODES + 255) / 256, 256, 0, stream>>>(cnt, dinv, hsb);
    gptr_kernel<<<(N_NODES + 255) / 256, 256, 0, stream>>>(batch, gptr);
    wsplit_kernel<<<(NLAYERS * DH * DH + 255) / 256, 256, 0, stream>>>(conv_w0, conv_ws,
                                                                       wthi, wtlo);
    xconv_kernel<<<(N_NODES * 32 + 255) / 256, 256, 0, stream>>>(x, xb);

    for (int l = 0; l < NLAYERS; ++l) {
        const float* b = (l == 0) ? conv_b0 : conv_bs + (size_t)(l - 1) * DH;
        mfma_gemm_kernel<<<1280, 512, 0, stream>>>(xb, wthi + (size_t)l * DH * DH,
                                                   wtlo + (size_t)l * DH * DH, dinv, hsb);
        agg_kernel<<<(N_NODES + 3) / 4, 256, 0, stream>>>(hsb, ninfo, dense, dinv, b, xb);
    }

    pool_kernel<<<N_GRAPHS, 256, 0, stream>>>(xb, gptr, lin_w, lin_b, (float*)d_out);
}

// Round 14
// 581.983 us; speedup vs baseline: 1.2067x; 1.1331x over previous
//
#include <hip/hip_runtime.h>

#define N_NODES 100000
#define N_EDGES 1600000
#define N_GRAPHS 512
#define DH 128
#define CAP 64             // per-node edge capacity in scratch (max in-deg ~42)
#define NLAYERS 6
#define NBUCK 196          // buckets of 512 nodes
#define BCAP 8960          // per-bucket edge capacity (mean 8163, +8 sigma)
#define CHUNK_A 4096
#define BLOCKS_A ((N_EDGES + CHUNK_A - 1) / CHUNK_A)   // 391
#define SENT_OFF (N_NODES << 8)      // sentinel byte-offset -> zero row at N_NODES
#define NT_TILES (N_NODES / 16)      // 6250

typedef short bf16x8 __attribute__((ext_vector_type(8)));
typedef float f32x4 __attribute__((ext_vector_type(4)));

// ---- bf16 helpers (RNE) ----
__device__ inline unsigned int pk_bf16x2(float a, float b) {
    unsigned int ua = __float_as_uint(a), ub = __float_as_uint(b);
    ua += 0x7fffu + ((ua >> 16) & 1u);
    ub += 0x7fffu + ((ub >> 16) & 1u);
    return (ua >> 16) | (ub & 0xffff0000u);
}
__device__ inline unsigned short bf16_rne(float f) {
    unsigned int u = __float_as_uint(f);
    u += 0x7fffu + ((u >> 16) & 1u);
    return (unsigned short)(u >> 16);
}
__device__ inline float bf_lo(unsigned int u) { return __uint_as_float(u << 16); }
__device__ inline float bf_hi(unsigned int u) { return __uint_as_float(u & 0xffff0000u); }

// ---- Pass A: radix partition edges into NBUCK buckets (by dst>>9), packed ----
// entry = (src << 9) | (dst & 511)
__global__ __launch_bounds__(256) void binA_kernel(const int* __restrict__ src,
                                                   const int* __restrict__ dst,
                                                   int* __restrict__ bcur,
                                                   int* __restrict__ part) {
    __shared__ int hist[NBUCK];
    __shared__ int base[NBUCK];
    int tid = threadIdx.x;
    int e0 = blockIdx.x * CHUNK_A;
    int myE = N_EDGES - e0; if (myE > CHUNK_A) myE = CHUNK_A;
    for (int b = tid; b < NBUCK; b += 256) hist[b] = 0;
    __syncthreads();
    for (int i = tid; i < myE; i += 256) {
        int d = dst[e0 + i];
        atomicAdd(&hist[d >> 9], 1);
    }
    __syncthreads();
    for (int b = tid; b < NBUCK; b += 256) {
        base[b] = atomicAdd(&bcur[b], hist[b]);
        hist[b] = 0;                      // reuse as local cursor
    }
    __syncthreads();
    for (int i = tid; i < myE; i += 256) {
        int s = src[e0 + i], d = dst[e0 + i];
        int b = d >> 9;
        int off = atomicAdd(&hist[b], 1);
        int pos = base[b] + off;
        if (pos < BCAP) part[(size_t)b * BCAP + pos] = (s << 9) | (d & 511);
    }
}

// ---- Pass B: scatter into CAP-padded scratch (entries = src<<8 byte offsets),
// then repack into DENSE per-node stream padded to round8(deg) with sentinels.
// ninfo[n] = {dense base, round8(deg)}.
__global__ __launch_bounds__(256) void binB_kernel(const int* __restrict__ part,
                                                   const int* __restrict__ bcur,
                                                   int* __restrict__ cnt,
                                                   int* __restrict__ scratch,
                                                   int2* __restrict__ ninfo,
                                                   int* __restrict__ gcursor,
                                                   int* __restrict__ dense) {
    __shared__ int lcnt[512];
    __shared__ int nbase[512];
    __shared__ int psum[64];
    __shared__ int bucket_base;
    int tid = threadIdx.x;
    int b = blockIdx.x;
    int node0 = b << 9;
    for (int i = tid; i < 512; i += 256) lcnt[i] = 0;
    __syncthreads();
    int m = bcur[b]; if (m > BCAP) m = BCAP;
    const int* p = part + (size_t)b * BCAP;
    for (int i = tid; i < m; i += 256) {
        int v = p[i];
        int dl = v & 511;
        int sv = (int)(((unsigned int)v) >> 9);
        int r = atomicAdd(&lcnt[dl], 1);
        if (r < CAP) scratch[(size_t)(node0 + dl) * CAP + r] = sv << 8;
    }
    __syncthreads();
    for (int i = tid; i < 512; i += 256) {
        int n = node0 + i;
        if (n < N_NODES) cnt[n] = lcnt[i];
    }
    if (tid < 64) {
        int acc = 0;
        int base = tid * 8;
#pragma unroll
        for (int i = 0; i < 8; ++i) {
            int dg = lcnt[base + i]; if (dg > CAP) dg = CAP;
            acc += (dg + 7) & ~7;
        }
        psum[tid] = acc;
    }
    __syncthreads();
    if (tid == 0) {
        int acc = 0;
        for (int i = 0; i < 64; ++i) { int t = psum[i]; psum[i] = acc; acc += t; }
        bucket_base = atomicAdd(gcursor, acc);
    }
    __syncthreads();
    if (tid < 64) {
        int off = psum[tid];
        int base = tid * 8;
#pragma unroll
        for (int i = 0; i < 8; ++i) {
            int dg = lcnt[base + i]; if (dg > CAP) dg = CAP;
            nbase[base + i] = off;
            off += (dg + 7) & ~7;
        }
    }
    __syncthreads();
    int bb = bucket_base;
    for (int i = tid; i < 512; i += 256) {
        int n = node0 + i;
        if (n < N_NODES) {
            int dg = lcnt[i]; if (dg > CAP) dg = CAP;
            ninfo[n] = make_int2(bb + nbase[i], (dg + 7) & ~7);
        }
    }
    // repack: 32 nodes per round, 8 threads per node
    for (int nb = 0; nb < 512; nb += 32) {
        int nl = nb + (tid >> 3);
        int n = node0 + nl;
        if (n < N_NODES) {
            int dg = lcnt[nl]; if (dg > CAP) dg = CAP;
            int r8 = (dg + 7) & ~7;
            int* dst = dense + bb + nbase[nl];
            for (int e = tid & 7; e < r8; e += 8)
                dst[e] = (e < dg) ? scratch[(size_t)n * CAP + e] : SENT_OFF;
        }
    }
}

// ---- dinv + zero the row-major sentinel row (64 u32) ----
__global__ void dinv_kernel(const int* __restrict__ cnt, float* __restrict__ dinv,
                            unsigned int* __restrict__ hsb) {
    int n = blockIdx.x * 256 + threadIdx.x;
    if (n < N_NODES) dinv[n] = rsqrtf((float)(cnt[n] + 1));
    if (n < 64) hsb[(size_t)N_NODES * 64 + n] = 0u;
}

// ---- W split: WThi/WTlo[l][c][k] = hi/lo bf16 of W_l[k][c] (transposed) ----
__global__ void wsplit_kernel(const float* __restrict__ w0, const float* __restrict__ ws,
                              unsigned short* __restrict__ wthi,
                              unsigned short* __restrict__ wtlo) {
    int i = blockIdx.x * 256 + threadIdx.x;
    if (i >= NLAYERS * DH * DH) return;
    int l = i >> 14;
    int r = i & 16383;
    int c = r >> 7, k = r & 127;
    const float* W = (l == 0) ? w0 : ws + (size_t)(l - 1) * DH * DH;
    float f = W[k * DH + c];
    unsigned short hi = bf16_rne(f);
    float hif = __uint_as_float(((unsigned int)hi) << 16);
    unsigned short lo = bf16_rne(f - hif);
    wthi[i] = hi;
    wtlo[i] = lo;
}

// ---- x fp32 -> packed bf16x2, SLICE-MAJOR xb: xb[(cu>>3)*N + node][cu&7] ----
__global__ void xconv_kernel(const float* __restrict__ x, unsigned int* __restrict__ xb) {
    int i = blockIdx.x * 256 + threadIdx.x;       // one uint2 (4 floats) per thread
    if (i >= N_NODES * 32) return;
    float4 v = *(const float4*)&x[(size_t)i * 4];
    int node = i >> 5;
    int cu = (i & 31) * 2;
    int ss = cu >> 3, o = cu & 7;
    uint2 ov = make_uint2(pk_bf16x2(v.x, v.y), pk_bf16x2(v.z, v.w));
    *(uint2*)&xb[((size_t)ss * N_NODES + node) * 8 + o] = ov;
}

// ---- MFMA GEMM: sliced B-loads (coalesced), ROW-MAJOR stores to hsb ----
// block = 512 thr (8 waves); wave w owns output u32-cols [w*8, w*8+8).
#define LOADB(v, kb, nd) \
    v = *(const bf16x8*)&Xb[(((size_t)(2*(kb) + (lk >> 1)) * N_NODES + (nd)) * 8) + (lk & 1) * 4];

__global__ __launch_bounds__(512) void mfma_gemm_kernel(const unsigned int* __restrict__ Xb,
                                                        const unsigned short* __restrict__ WThi,
                                                        const unsigned short* __restrict__ WTlo,
                                                        const float* __restrict__ dinv,
                                                        unsigned int* __restrict__ Yb) {
    int w = threadIdx.x >> 6;
    int lane = threadIdx.x & 63;
    int l15 = lane & 15, lk = lane >> 4;          // lk in 0..3
    int wc = w * 16 + l15;                        // A row (output dim)
    bf16x8 ahi[4], alo[4];
#pragma unroll
    for (int kb = 0; kb < 4; ++kb) {
        int k0 = kb * 32 + lk * 8;
        ahi[kb] = *(const bf16x8*)&WThi[wc * DH + k0];
        alo[kb] = *(const bf16x8*)&WTlo[wc * DH + k0];
    }
    int nt = blockIdx.x;
    if (nt >= NT_TILES) return;
    int node = nt * 16 + l15;
    bf16x8 b0, b1, b2, b3;
    LOADB(b0, 0, node); LOADB(b1, 1, node); LOADB(b2, 2, node); LOADB(b3, 3, node);
    for (;;) {
        int ntn = nt + gridDim.x;
        bool hn = ntn < NT_TILES;
        int noden = ntn * 16 + l15;
        bf16x8 n0 = b0, n1 = b1, n2 = b2, n3 = b3;
        if (hn) { LOADB(n0, 0, noden); LOADB(n1, 1, noden); LOADB(n2, 2, noden); LOADB(n3, 3, noden); }
        float dn = dinv[node];
        f32x4 acc = {0.f, 0.f, 0.f, 0.f};
        acc = __builtin_amdgcn_mfma_f32_16x16x32_bf16(ahi[0], b0, acc, 0, 0, 0);
        acc = __builtin_amdgcn_mfma_f32_16x16x32_bf16(alo[0], b0, acc, 0, 0, 0);
        acc = __builtin_amdgcn_mfma_f32_16x16x32_bf16(ahi[1], b1, acc, 0, 0, 0);
        acc = __builtin_amdgcn_mfma_f32_16x16x32_bf16(alo[1], b1, acc, 0, 0, 0);
        acc = __builtin_amdgcn_mfma_f32_16x16x32_bf16(ahi[2], b2, acc, 0, 0, 0);
        acc = __builtin_amdgcn_mfma_f32_16x16x32_bf16(alo[2], b2, acc, 0, 0, 0);
        acc = __builtin_amdgcn_mfma_f32_16x16x32_bf16(ahi[3], b3, acc, 0, 0, 0);
        acc = __builtin_amdgcn_mfma_f32_16x16x32_bf16(alo[3], b3, acc, 0, 0, 0);
        uint2 ov = make_uint2(pk_bf16x2(acc[0] * dn, acc[1] * dn),
                              pk_bf16x2(acc[2] * dn, acc[3] * dn));
        *(uint2*)&Yb[(size_t)node * 64 + w * 8 + lk * 2] = ov;   // row-major
        if (!hn) break;
        nt = ntn; node = noden; b0 = n0; b1 = n1; b2 = n2; b3 = n3;
    }
}

// ---- aggregation: wave = 1 node, full-row gathers (256B/instr, 2 lines/edge),
// dense per-node sentinel-padded indices via SCALAR loads; SLICED output ----
__global__ __launch_bounds__(256) void agg_kernel(const unsigned int* __restrict__ hs,
                                                  const int2* __restrict__ ninfo,
                                                  const int* __restrict__ dense,
                                                  const float* __restrict__ dinv,
                                                  const float* __restrict__ bias,
                                                  unsigned int* __restrict__ out) {
    int node = blockIdx.x * 4 + (threadIdx.x >> 6);
    if (node >= N_NODES) return;
    int lane = threadIdx.x & 63;
    int2 gi = ninfo[node];
    int dbase = __builtin_amdgcn_readfirstlane(gi.x);
    int r8d   = __builtin_amdgcn_readfirstlane(gi.y);
    const int* row = dense + dbase;                // wave-uniform -> scalar loads
    const char* hb = (const char*)hs;
    int l4 = lane * 4;
    // hoisted epilogue operands
    float dn = dinv[node];
    unsigned int us = hs[(size_t)node * 64 + lane];    // self term
    float bx = bias[lane * 2], by = bias[lane * 2 + 1];
    float ax = 0.f, ay = 0.f;
    for (int e = 0; e < r8d; e += 8) {
        int o0 = row[e + 0], o1 = row[e + 1], o2 = row[e + 2], o3 = row[e + 3];
        int o4 = row[e + 4], o5 = row[e + 5], o6 = row[e + 6], o7 = row[e + 7];
        unsigned int u0 = *(const unsigned int*)(hb + (o0 + l4));
        unsigned int u1 = *(const unsigned int*)(hb + (o1 + l4));
        unsigned int u2 = *(const unsigned int*)(hb + (o2 + l4));
        unsigned int u3 = *(const unsigned int*)(hb + (o3 + l4));
        unsigned int u4 = *(const unsigned int*)(hb + (o4 + l4));
        unsigned int u5 = *(const unsigned int*)(hb + (o5 + l4));
        unsigned int u6 = *(const unsigned int*)(hb + (o6 + l4));
        unsigned int u7 = *(const unsigned int*)(hb + (o7 + l4));
        ax += ((bf_lo(u0) + bf_lo(u1)) + (bf_lo(u2) + bf_lo(u3)))
            + ((bf_lo(u4) + bf_lo(u5)) + (bf_lo(u6) + bf_lo(u7)));
        ay += ((bf_hi(u0) + bf_hi(u1)) + (bf_hi(u2) + bf_hi(u3)))
            + ((bf_hi(u4) + bf_hi(u5)) + (bf_hi(u6) + bf_hi(u7)));
    }
    float sx = ax + bf_lo(us), sy = ay + bf_hi(us);
    float ox = fmaxf(fmaf(sx, dn, bx), 0.f);
    float oy = fmaxf(fmaf(sy, dn, by), 0.f);
    // sliced write: slice = lane>>3, u32-in-slice = lane&7
    out[((size_t)(lane >> 3) * N_NODES + node) * 8 + (lane & 7)] = pk_bf16x2(ox, oy);
}

// ---- graph boundaries from sorted batch ----
__global__ void gptr_kernel(const int* __restrict__ batch, int* __restrict__ gptr) {
    int n = blockIdx.x * 256 + threadIdx.x;
    if (n >= N_NODES) return;
    int b1 = batch[n];
    if (n == 0) {
        for (int g = 0; g <= b1; ++g) gptr[g] = 0;
    } else {
        int b0 = batch[n - 1];
        for (int g = b0 + 1; g <= b1; ++g) gptr[g] = n;
    }
    if (n == N_NODES - 1) {
        for (int g = b1 + 1; g <= N_GRAPHS; ++g) gptr[g] = N_NODES;
    }
}

// ---- pooling + linear head (reads SLICED packed bf16 h) ----
__global__ __launch_bounds__(256) void pool_kernel(const unsigned int* __restrict__ h,
                                                   const int* __restrict__ gptr,
                                                   const float* __restrict__ lin_w,
                                                   const float* __restrict__ lin_b,
                                                   float* __restrict__ out) {
    __shared__ float part[4];
    int g = blockIdx.x;
    int s = gptr[g], epos = gptr[g + 1];
    int w = threadIdx.x >> 6, lane = threadIdx.x & 63;
    size_t sbase = (size_t)(lane >> 3) * N_NODES * 8 + (lane & 7);
    float2 wv = *(const float2*)(lin_w + lane * 2);
    float acc = 0.f;
    for (int n = s + w; n < epos; n += 4) {
        unsigned int u = h[sbase + (size_t)n * 8];
        acc += bf_lo(u) * wv.x + bf_hi(u) * wv.y;
    }
#pragma unroll
    for (int off = 32; off > 0; off >>= 1) acc += __shfl_down(acc, off, 64);
    if (lane == 0) part[w] = acc;
    __syncthreads();
    if (threadIdx.x == 0) {
        float t = (part[0] + part[1]) + (part[2] + part[3]);
        float c = (float)(epos - s);
        if (c < 1.f) c = 1.f;
        out[g] = t / c + lin_b[0];
    }
}

extern "C" void kernel_launch(void* const* d_in, const int* in_sizes, int n_in,
                              void* d_out, int out_size, void* d_ws, size_t ws_size,
                              hipStream_t stream) {
    const float* x       = (const float*)d_in[0];
    const int*   eidx    = (const int*)d_in[1];
    const int*   batch   = (const int*)d_in[2];
    const float* conv_w0 = (const float*)d_in[3];
    const float* conv_b0 = (const float*)d_in[4];
    const float* conv_ws = (const float*)d_in[5];
    const float* conv_bs = (const float*)d_in[6];
    const float* lin_w   = (const float*)d_in[7];
    const float* lin_b   = (const float*)d_in[8];
    const int* srcI = eidx;
    const int* dstI = eidx + N_EDGES;

    char* ws = (char*)d_ws;
    size_t off = 0;
    auto alloc = [&](size_t bytes) {
        void* p = ws + off;
        off += (bytes + 255) & ~(size_t)255;
        return p;
    };
    unsigned int*  xb      = (unsigned int*)alloc((size_t)N_NODES * 64 * 4);       // sliced
    unsigned int*  hsb     = (unsigned int*)alloc((size_t)(N_NODES + 1) * 64 * 4); // row-major + sentinel
    int*           scratch = (int*)alloc((size_t)N_NODES * CAP * 4);
    int*           dense   = (int*)alloc((size_t)(N_EDGES + 8 * N_NODES) * 4);
    int*           part    = (int*)alloc((size_t)NBUCK * BCAP * 4);
    int*           cnt     = (int*)alloc((size_t)N_NODES * 4);
    float*         dinv    = (float*)alloc((size_t)N_NODES * 4);
    int*           bcur    = (int*)alloc((size_t)(NBUCK + 1) * 4);  // +1: dense cursor
    int*           gptr    = (int*)alloc((size_t)(N_GRAPHS + 1) * 4);
    int2*          ninfo   = (int2*)alloc((size_t)N_NODES * 8);
    unsigned short* wthi = (unsigned short*)alloc((size_t)NLAYERS * DH * DH * 2);
    unsigned short* wtlo = (unsigned short*)alloc((size_t)NLAYERS * DH * DH * 2);
    int* gcursor = bcur + NBUCK;
    (void)ws_size; (void)in_sizes; (void)n_in; (void)out_size;

    hipMemsetAsync(bcur, 0, (size_t)(NBUCK + 1) * 4, stream);

    binA_kernel<<<BLOCKS_A, 256, 0, stream>>>(srcI, dstI, bcur, part);
    binB_kernel<<<NBUCK, 256, 0, stream>>>(part, bcur, cnt, scratch, ninfo, gcursor, dense);
    dinv_kernel<<<(N_NODES + 255) / 256, 256, 0, stream>>>(cnt, dinv, hsb);
    gptr_kernel<<<(N_NODES + 255) / 256, 256, 0, stream>>>(batch, gptr);
    wsplit_kernel<<<(NLAYERS * DH * DH + 255) / 256, 256, 0, stream>>>(conv_w0, conv_ws,
                                                                       wthi, wtlo);
    xconv_kernel<<<(N_NODES * 32 + 255) / 256, 256, 0, stream>>>(x, xb);

    for (int l = 0; l < NLAYERS; ++l) {
        const float* b = (l == 0) ? conv_b0 : conv_bs + (size_t)(l - 1) * DH;
        mfma_gemm_kernel<<<1280, 512, 0, stream>>>(xb, wthi + (size_t)l * DH * DH,
                                                   wtlo + (size_t)l * DH * DH, dinv, hsb);
        agg_kernel<<<(N_NODES + 3) / 4, 256, 0, stream>>>(hsb, ninfo, dense, dinv, b, xb);
    }

    pool_kernel<<<N_GRAPHS, 256, 0, stream>>>(xb, gptr, lin_w, lin_b, (float*)d_out);
}